// Round 1
// baseline (413.927 us; speedup 1.0000x reference)
//
#include <hip/hip_runtime.h>
#include <hip/hip_bf16.h>

// ---------------------------------------------------------------------------
// Fused LN + QKV projection + MHA with the reference's view-scramble epilogue.
//
// Key algebraic reduction: out[b][s2][d2] = sum_{j<8} att_wide[b][h=s2>>8]
//   [q=(s2&255)*8 + (d2>>7)][(d2&127)*8 + j].  The 8-group sum commutes with
//   P@V, so V's effective width per head is 128 via column-group-summed Wv.
// ---------------------------------------------------------------------------

typedef __bf16 bf16_t;
typedef __bf16 bf16x8 __attribute__((ext_vector_type(8)));
typedef __bf16 bf16x4 __attribute__((ext_vector_type(4)));
typedef float  f32x4  __attribute__((ext_vector_type(4)));

#define AS1 __attribute__((address_space(1)))
#define AS3 __attribute__((address_space(3)))

static __device__ __forceinline__ void gload_lds16(const void* g, void* l) {
  __builtin_amdgcn_global_load_lds((const AS1 void*)g, (AS3 void*)l, 16, 0, 0);
}

// ---- WvSum: tmp[k][n] = sum_{j<8} Wv[k][(n>>7)*1024 + (n&127)*8 + j] -------
__global__ __launch_bounds__(256) void k_wvsum(const float* __restrict__ Wv,
                                               float* __restrict__ tmp) {
  const int k = blockIdx.x;
  const float* row = Wv + (size_t)k * 8192;
  float* orow = tmp + (size_t)k * 1024;
  #pragma unroll
  for (int p = 0; p < 4; ++p) {
    const int n = p * 256 + threadIdx.x;
    const int base = ((n >> 7) << 10) + ((n & 127) << 3);
    const float4 a = *(const float4*)(row + base);
    const float4 b = *(const float4*)(row + base + 4);
    orow[n] = a.x + a.y + a.z + a.w + b.x + b.y + b.z + b.w;
  }
}

// ---- transpose+cvt: dst[c][r] = bf16(src[r][c]), 1024x1024 -----------------
__global__ __launch_bounds__(256) void k_transpose(const float* __restrict__ src,
                                                   bf16_t* __restrict__ dst) {
  __shared__ float tile[32][33];
  const int tx = threadIdx.x, ty = threadIdx.y;
  const int c0 = blockIdx.x * 32, r0 = blockIdx.y * 32;
  #pragma unroll
  for (int j = 0; j < 4; ++j)
    tile[ty + j * 8][tx] = src[(size_t)(r0 + ty + j * 8) * 1024 + c0 + tx];
  __syncthreads();
  #pragma unroll
  for (int j = 0; j < 4; ++j)
    dst[(size_t)(c0 + ty + j * 8) * 1024 + r0 + tx] = (bf16_t)tile[tx][ty + j * 8];
}

// ---- bias concat: [bq | bk | group-summed bv] ------------------------------
__global__ __launch_bounds__(256) void k_bias(const float* __restrict__ bq,
                                              const float* __restrict__ bk,
                                              const float* __restrict__ bv,
                                              float* __restrict__ bias) {
  const int i = blockIdx.x * 256 + threadIdx.x;
  float v;
  if (i < 1024) v = bq[i];
  else if (i < 2048) v = bk[i - 1024];
  else {
    const int n = i - 2048;
    const int base = ((n >> 7) << 10) + ((n & 127) << 3);
    v = 0.f;
    #pragma unroll
    for (int j = 0; j < 8; ++j) v += bv[base + j];
  }
  bias[i] = v;
}

// ---- LayerNorm fp32 -> bf16 ------------------------------------------------
__global__ __launch_bounds__(256) void k_ln(const float* __restrict__ x,
                                            const float* __restrict__ gamma,
                                            const float* __restrict__ beta,
                                            bf16_t* __restrict__ xn) {
  const int row = blockIdx.x, tid = threadIdx.x;
  const float4 v = ((const float4*)x)[(size_t)row * 256 + tid];
  float s  = v.x + v.y + v.z + v.w;
  float ss = v.x * v.x + v.y * v.y + v.z * v.z + v.w * v.w;
  #pragma unroll
  for (int off = 32; off >= 1; off >>= 1) {
    s  += __shfl_down(s, off);
    ss += __shfl_down(ss, off);
  }
  __shared__ float red[8];
  if ((tid & 63) == 0) { red[tid >> 6] = s; red[4 + (tid >> 6)] = ss; }
  __syncthreads();
  s  = red[0] + red[1] + red[2] + red[3];
  ss = red[4] + red[5] + red[6] + red[7];
  const float mu   = s * (1.0f / 1024.0f);
  const float rstd = rsqrtf(ss * (1.0f / 1024.0f) - mu * mu + 1e-5f);
  const float4 g = ((const float4*)gamma)[tid];
  const float4 b = ((const float4*)beta)[tid];
  bf16x4 o;
  o[0] = (bf16_t)((v.x - mu) * rstd * g.x + b.x);
  o[1] = (bf16_t)((v.y - mu) * rstd * g.y + b.y);
  o[2] = (bf16_t)((v.z - mu) * rstd * g.z + b.z);
  o[3] = (bf16_t)((v.w - mu) * rstd * g.w + b.w);
  *(bf16x4*)(xn + (size_t)row * 1024 + tid * 4) = o;
}

// ---- QKV GEMM: [8192,1024] x [1024,3072] (B given transposed) + bias -------
// 128x128 tile, BK=64, 4 waves (2x2 of 64x64), global_load_lds w=16,
// T2 XOR swizzle applied via pre-swizzled global source (rule #21).
__global__ __launch_bounds__(256) void k_gemm(const bf16_t* __restrict__ Ag,
                                              const bf16_t* __restrict__ Bg,
                                              const float* __restrict__ bias,
                                              bf16_t* __restrict__ Cg) {
  __shared__ __align__(16) bf16_t As[128 * 64];
  __shared__ __align__(16) bf16_t Bs[128 * 64];
  const int tid = threadIdx.x, w = tid >> 6, l = tid & 63;
  const int m0 = blockIdx.y * 128, n0 = blockIdx.x * 128;
  const int wm = (w >> 1) * 64, wn = (w & 1) * 64;
  const int qr = l & 15, ko = (l >> 4) * 8;
  const int srow   = l >> 3;                   // row within 8-row staging group
  const int schunk = 8 * ((l & 7) ^ srow);     // inverse-swizzled source chunk

  f32x4 acc[4][4];
  #pragma unroll
  for (int i = 0; i < 4; ++i)
    #pragma unroll
    for (int j = 0; j < 4; ++j) acc[i][j] = (f32x4){0.f, 0.f, 0.f, 0.f};

  for (int kt = 0; kt < 1024; kt += 64) {
    #pragma unroll
    for (int c = 0; c < 4; ++c) {
      const int cc = w * 4 + c;
      const int row = cc * 8 + srow;
      gload_lds16(Ag + (size_t)(m0 + row) * 1024 + kt + schunk, As + cc * 512);
      gload_lds16(Bg + (size_t)(n0 + row) * 1024 + kt + schunk, Bs + cc * 512);
    }
    __syncthreads();
    #pragma unroll
    for (int kk = 0; kk < 2; ++kk) {
      const int eo = (kk * 32 + ko) ^ ((qr & 7) << 3);   // swizzled read
      bf16x8 afr[4], bfr[4];
      #pragma unroll
      for (int x = 0; x < 4; ++x) {
        afr[x] = *(const bf16x8*)(As + (wm + x * 16 + qr) * 64 + eo);
        bfr[x] = *(const bf16x8*)(Bs + (wn + x * 16 + qr) * 64 + eo);
      }
      #pragma unroll
      for (int mi = 0; mi < 4; ++mi)
        #pragma unroll
        for (int ni = 0; ni < 4; ++ni)
          acc[mi][ni] = __builtin_amdgcn_mfma_f32_16x16x32_bf16(
              afr[mi], bfr[ni], acc[mi][ni], 0, 0, 0);
    }
    __syncthreads();
  }
  #pragma unroll
  for (int ni = 0; ni < 4; ++ni) {
    const int col = n0 + wn + ni * 16 + qr;
    const float bc = bias[col];
    #pragma unroll
    for (int mi = 0; mi < 4; ++mi)
      #pragma unroll
      for (int r = 0; r < 4; ++r) {
        const int row = m0 + wm + mi * 16 + (l >> 4) * 4 + r;
        Cg[(size_t)row * 3072 + col] = (bf16_t)(acc[mi][ni][r] + bc);
      }
  }
}

// ---- Flash attention, dk=dv=128, KVBLK=64, 4 waves x 32 q-rows -------------
__global__ __launch_bounds__(256) void k_attn(const bf16_t* __restrict__ QKV,
                                              float* __restrict__ out) {
  __shared__ __align__(16) bf16_t Kt[64 * 128];     // [t][k], swizzled rows
  __shared__ __align__(16) bf16_t Vt[128 * 64];     // [dg][t], swizzled rows
  __shared__ __align__(16) bf16_t Pl[4][32 * 64];   // per-wave P, swizzled

  const int tid = threadIdx.x, w = tid >> 6, l = tid & 63;
  const int b = blockIdx.y >> 3, h = blockIdx.y & 7;
  const int q0 = blockIdx.x * 128 + w * 32;
  const int qr = l & 15, ko = (l >> 4) * 8;

  const bf16_t* Qb = QKV + (size_t)b * 2048 * 3072 + h * 128;
  const bf16_t* Kb = Qb + 1024;
  const bf16_t* Vb = Qb + 2048;

  bf16x8 aq[2][4];
  #pragma unroll
  for (int mi = 0; mi < 2; ++mi)
    #pragma unroll
    for (int kk = 0; kk < 4; ++kk)
      aq[mi][kk] = *(const bf16x8*)(Qb + (size_t)(q0 + mi * 16 + qr) * 3072 + kk * 32 + ko);

  f32x4 o[2][8];
  float mrun[2][4], lrun[2][4];
  #pragma unroll
  for (int mi = 0; mi < 2; ++mi) {
    #pragma unroll
    for (int ni = 0; ni < 8; ++ni) o[mi][ni] = (f32x4){0.f, 0.f, 0.f, 0.f};
    #pragma unroll
    for (int r = 0; r < 4; ++r) { mrun[mi][r] = -1e30f; lrun[mi][r] = 0.f; }
  }

  const int krow_in = l >> 4;       // K staging: sub-row within 4-row group
  const int kchunk  = l & 15;       // 16B chunk in 256B K row
  const int vt_loc  = w * 16 + qr;  // V staging: t owned by this thread

  for (int t0 = 0; t0 < 2048; t0 += 64) {
    // --- K tile: global_load_lds, source pre-swizzled ---
    #pragma unroll
    for (int c = 0; c < 4; ++c) {
      const int cc = w * 4 + c;
      const int row = cc * 4 + krow_in;                 // 0..63
      const int selem = 8 * (kchunk ^ (row & 7));
      gload_lds16(Kb + (size_t)(t0 + row) * 3072 + selem, Kt + cc * 512);
    }
    // --- V tile: reg-staged transpose, conflict-mitigated lane assignment ---
    #pragma unroll
    for (int p = 0; p < 4; ++p) {
      const int chunk = (l >> 4) * 4 + p;               // 0..15
      const bf16x8 v8 = *(const bf16x8*)(Vb + (size_t)(t0 + vt_loc) * 3072 + chunk * 8);
      #pragma unroll
      for (int j = 0; j < 8; ++j) {
        const int dg = chunk * 8 + j;                   // dg&7 == j
        Vt[dg * 64 + (vt_loc ^ (j << 3))] = v8[j];
      }
    }
    __syncthreads();

    // --- S = Q K^T ---
    f32x4 s[2][4];
    #pragma unroll
    for (int mi = 0; mi < 2; ++mi)
      #pragma unroll
      for (int ni = 0; ni < 4; ++ni) s[mi][ni] = (f32x4){0.f, 0.f, 0.f, 0.f};
    #pragma unroll
    for (int kk = 0; kk < 4; ++kk) {
      const int eo = (kk * 32 + ko) ^ ((qr & 7) << 3);
      #pragma unroll
      for (int ni = 0; ni < 4; ++ni) {
        const bf16x8 bfr = *(const bf16x8*)(Kt + (ni * 16 + qr) * 128 + eo);
        s[0][ni] = __builtin_amdgcn_mfma_f32_16x16x32_bf16(aq[0][kk], bfr, s[0][ni], 0, 0, 0);
        s[1][ni] = __builtin_amdgcn_mfma_f32_16x16x32_bf16(aq[1][kk], bfr, s[1][ni], 0, 0, 0);
      }
    }

    // --- online softmax + P -> LDS (bf16) ---
    const float sc = 0.08838834764831845f;   // 1/sqrt(128)
    #pragma unroll
    for (int mi = 0; mi < 2; ++mi)
      #pragma unroll
      for (int r = 0; r < 4; ++r) {
        const float z0 = s[mi][0][r] * sc, z1 = s[mi][1][r] * sc;
        const float z2 = s[mi][2][r] * sc, z3 = s[mi][3][r] * sc;
        float mx = fmaxf(fmaxf(z0, z1), fmaxf(z2, z3));
        #pragma unroll
        for (int off = 1; off < 16; off <<= 1) mx = fmaxf(mx, __shfl_xor(mx, off));
        const float mold = mrun[mi][r];
        const float mnew = fmaxf(mold, mx);
        const float fac  = __expf(mold - mnew);
        const float p0 = __expf(z0 - mnew), p1 = __expf(z1 - mnew);
        const float p2 = __expf(z2 - mnew), p3 = __expf(z3 - mnew);
        float ps = p0 + p1 + p2 + p3;
        #pragma unroll
        for (int off = 1; off < 16; off <<= 1) ps += __shfl_xor(ps, off);
        lrun[mi][r] = lrun[mi][r] * fac + ps;
        mrun[mi][r] = mnew;
        #pragma unroll
        for (int ni = 0; ni < 8; ++ni) o[mi][ni][r] *= fac;
        const int prow = mi * 16 + (l >> 4) * 4 + r;
        const int px = (prow & 7) << 3;
        bf16_t* pr = &Pl[w][prow * 64];
        pr[(0 * 16 + qr) ^ px] = (bf16_t)p0;
        pr[(1 * 16 + qr) ^ px] = (bf16_t)p1;
        pr[(2 * 16 + qr) ^ px] = (bf16_t)p2;
        pr[(3 * 16 + qr) ^ px] = (bf16_t)p3;
      }

    // --- O += P V ---
    #pragma unroll
    for (int kk = 0; kk < 2; ++kk) {
      const int eo = (kk * 32 + ko) ^ ((qr & 7) << 3);
      const bf16x8 ap0 = *(const bf16x8*)(&Pl[w][(0 * 16 + qr) * 64 + eo]);
      const bf16x8 ap1 = *(const bf16x8*)(&Pl[w][(16 + qr) * 64 + eo]);
      #pragma unroll
      for (int ni = 0; ni < 8; ++ni) {
        const bf16x8 bv = *(const bf16x8*)(Vt + (ni * 16 + qr) * 64 + eo);
        o[0][ni] = __builtin_amdgcn_mfma_f32_16x16x32_bf16(ap0, bv, o[0][ni], 0, 0, 0);
        o[1][ni] = __builtin_amdgcn_mfma_f32_16x16x32_bf16(ap1, bv, o[1][ni], 0, 0, 0);
      }
    }
    __syncthreads();
  }

  // --- epilogue: normalize + scrambled (contiguous-row) write ---
  #pragma unroll
  for (int mi = 0; mi < 2; ++mi)
    #pragma unroll
    for (int r = 0; r < 4; ++r) {
      const int qrow = q0 + mi * 16 + (l >> 4) * 4 + r;
      const float inv = 1.0f / lrun[mi][r];
      float* orow = out + ((size_t)b * 2048 + h * 256 + (qrow >> 3)) * 1024
                  + (qrow & 7) * 128;
      #pragma unroll
      for (int ni = 0; ni < 8; ++ni)
        orow[ni * 16 + qr] = o[mi][ni][r] * inv;
    }
}

// ---------------------------------------------------------------------------
extern "C" void kernel_launch(void* const* d_in, const int* in_sizes, int n_in,
                              void* d_out, int out_size, void* d_ws, size_t ws_size,
                              hipStream_t stream) {
  const float* x     = (const float*)d_in[0];
  const float* Wq    = (const float*)d_in[1];
  const float* bq    = (const float*)d_in[2];
  const float* Wk    = (const float*)d_in[3];
  const float* bk    = (const float*)d_in[4];
  const float* Wv    = (const float*)d_in[5];
  const float* bv    = (const float*)d_in[6];
  const float* gamma = (const float*)d_in[7];
  const float* beta  = (const float*)d_in[8];
  float* out = (float*)d_out;

  char* ws = (char*)d_ws;
  size_t off = 0;
  bf16_t* WT  = (bf16_t*)(ws + off); off += (size_t)3072 * 1024 * 2;  // W^T bf16
  float*  bias = (float*)(ws + off); off += (size_t)3072 * 4;
  off = (off + 255) & ~(size_t)255;
  bf16_t* xn  = (bf16_t*)(ws + off); off += (size_t)8192 * 1024 * 2;  // LN out
  bf16_t* QKV = (bf16_t*)(ws + off); off += (size_t)8192 * 3072 * 2;  // projections
  float*  tmp = (float*)(ws + off);  off += (size_t)1024 * 1024 * 4;  // WvSum fp32

  const dim3 tb(32, 8), tg(32, 32);
  k_wvsum<<<1024, 256, 0, stream>>>(Wv, tmp);
  k_transpose<<<tg, tb, 0, stream>>>(Wq, WT);
  k_transpose<<<tg, tb, 0, stream>>>(Wk, WT + (size_t)1024 * 1024);
  k_transpose<<<tg, tb, 0, stream>>>(tmp, WT + (size_t)2048 * 1024);
  k_bias<<<12, 256, 0, stream>>>(bq, bk, bv, bias);
  k_ln<<<8192, 256, 0, stream>>>(x, gamma, beta, xn);
  k_gemm<<<dim3(24, 64), 256, 0, stream>>>(xn, WT, bias, QKV);
  k_attn<<<dim3(16, 32), 256, 0, stream>>>(QKV, out);
}

// Round 5
// 343.139 us; speedup vs baseline: 1.2063x; 1.2063x over previous
//
#include <hip/hip_runtime.h>
#include <hip/hip_bf16.h>

// ---------------------------------------------------------------------------
// Fused LN + QKV projection + MHA with the reference's view-scramble epilogue.
//
// out[b][s2][d2] = sum_{j<8} att_wide[b][s2>>8][(s2&255)*8+(d2>>7)][(d2&127)*8+j]
// The 8-group sum commutes with P@V -> V effective width 128 via group-summed Wv.
//
// Attention: swapped QK^T (S^T, q = lane&15), in-register online softmax (T13
// defer-max), zero-move P fragments feeding 16x16x16 PV MFMAs, V transposed
// into LDS via reg-staging + shfl pairing (no tr_read - semantics provable),
// counted-vmcnt pipeline (T4): 3 K bufs (global_load_lds) + 2 VT bufs,
// one s_waitcnt vmcnt(8)+s_barrier per tile. T5 setprio on MFMA clusters.
// ---------------------------------------------------------------------------

typedef __bf16 bf16_t;
typedef __bf16 bf16x8 __attribute__((ext_vector_type(8)));
typedef __bf16 bf16x4 __attribute__((ext_vector_type(4)));
typedef short  s16x4  __attribute__((ext_vector_type(4)));
typedef float  f32x4  __attribute__((ext_vector_type(4)));
typedef unsigned short u16;
typedef unsigned int   u32;

#define AS1 __attribute__((address_space(1)))
#define AS3 __attribute__((address_space(3)))

static __device__ __forceinline__ void gload_lds16(const void* g, void* l) {
  __builtin_amdgcn_global_load_lds((const AS1 void*)g, (AS3 void*)l, 16, 0, 0);
}

static __device__ __forceinline__ float vmax4(f32x4 v) {
  return fmaxf(fmaxf(v[0], v[1]), fmaxf(v[2], v[3]));
}

#define MFMA16(a, b, c) __builtin_amdgcn_mfma_f32_16x16x16bf16_1k(a, b, c, 0, 0, 0)

// ---- WvSum: tmp[k][n] = sum_{j<8} Wv[k][(n>>7)*1024 + (n&127)*8 + j] -------
__global__ __launch_bounds__(256) void k_wvsum(const float* __restrict__ Wv,
                                               float* __restrict__ tmp) {
  const int k = blockIdx.x;
  const float* row = Wv + (size_t)k * 8192;
  float* orow = tmp + (size_t)k * 1024;
  #pragma unroll
  for (int p = 0; p < 4; ++p) {
    const int n = p * 256 + threadIdx.x;
    const int base = ((n >> 7) << 10) + ((n & 127) << 3);
    const float4 a = *(const float4*)(row + base);
    const float4 b = *(const float4*)(row + base + 4);
    orow[n] = a.x + a.y + a.z + a.w + b.x + b.y + b.z + b.w;
  }
}

// ---- transpose+cvt: dst[c][r] = bf16(src[r][c]), 1024x1024 -----------------
__global__ __launch_bounds__(256) void k_transpose(const float* __restrict__ src,
                                                   bf16_t* __restrict__ dst) {
  __shared__ float tile[32][33];
  const int tx = threadIdx.x, ty = threadIdx.y;
  const int c0 = blockIdx.x * 32, r0 = blockIdx.y * 32;
  #pragma unroll
  for (int j = 0; j < 4; ++j)
    tile[ty + j * 8][tx] = src[(size_t)(r0 + ty + j * 8) * 1024 + c0 + tx];
  __syncthreads();
  #pragma unroll
  for (int j = 0; j < 4; ++j)
    dst[(size_t)(c0 + ty + j * 8) * 1024 + r0 + tx] = (bf16_t)tile[tx][ty + j * 8];
}

// ---- bias concat: [bq | bk | group-summed bv] ------------------------------
__global__ __launch_bounds__(256) void k_bias(const float* __restrict__ bq,
                                              const float* __restrict__ bk,
                                              const float* __restrict__ bv,
                                              float* __restrict__ bias) {
  const int i = blockIdx.x * 256 + threadIdx.x;
  float v;
  if (i < 1024) v = bq[i];
  else if (i < 2048) v = bk[i - 1024];
  else {
    const int n = i - 2048;
    const int base = ((n >> 7) << 10) + ((n & 127) << 3);
    v = 0.f;
    #pragma unroll
    for (int j = 0; j < 8; ++j) v += bv[base + j];
  }
  bias[i] = v;
}

// ---- LayerNorm fp32 -> bf16 ------------------------------------------------
__global__ __launch_bounds__(256) void k_ln(const float* __restrict__ x,
                                            const float* __restrict__ gamma,
                                            const float* __restrict__ beta,
                                            bf16_t* __restrict__ xn) {
  const int row = blockIdx.x, tid = threadIdx.x;
  const float4 v = ((const float4*)x)[(size_t)row * 256 + tid];
  float s  = v.x + v.y + v.z + v.w;
  float ss = v.x * v.x + v.y * v.y + v.z * v.z + v.w * v.w;
  #pragma unroll
  for (int off = 32; off >= 1; off >>= 1) {
    s  += __shfl_down(s, off);
    ss += __shfl_down(ss, off);
  }
  __shared__ float red[8];
  if ((tid & 63) == 0) { red[tid >> 6] = s; red[4 + (tid >> 6)] = ss; }
  __syncthreads();
  s  = red[0] + red[1] + red[2] + red[3];
  ss = red[4] + red[5] + red[6] + red[7];
  const float mu   = s * (1.0f / 1024.0f);
  const float rstd = rsqrtf(ss * (1.0f / 1024.0f) - mu * mu + 1e-5f);
  const float4 g = ((const float4*)gamma)[tid];
  const float4 b = ((const float4*)beta)[tid];
  bf16x4 o;
  o[0] = (bf16_t)((v.x - mu) * rstd * g.x + b.x);
  o[1] = (bf16_t)((v.y - mu) * rstd * g.y + b.y);
  o[2] = (bf16_t)((v.z - mu) * rstd * g.z + b.z);
  o[3] = (bf16_t)((v.w - mu) * rstd * g.w + b.w);
  *(bf16x4*)(xn + (size_t)row * 1024 + tid * 4) = o;
}

// ---- QKV GEMM: [8192,1024] x [1024,3072] (B given transposed) + bias -------
__global__ __launch_bounds__(256) void k_gemm(const bf16_t* __restrict__ Ag,
                                              const bf16_t* __restrict__ Bg,
                                              const float* __restrict__ bias,
                                              bf16_t* __restrict__ Cg) {
  __shared__ __align__(16) bf16_t As[128 * 64];
  __shared__ __align__(16) bf16_t Bs[128 * 64];
  const int tid = threadIdx.x, w = tid >> 6, l = tid & 63;
  const int m0 = blockIdx.y * 128, n0 = blockIdx.x * 128;
  const int wm = (w >> 1) * 64, wn = (w & 1) * 64;
  const int qr = l & 15, ko = (l >> 4) * 8;
  const int srow   = l >> 3;
  const int schunk = 8 * ((l & 7) ^ srow);

  f32x4 acc[4][4];
  #pragma unroll
  for (int i = 0; i < 4; ++i)
    #pragma unroll
    for (int j = 0; j < 4; ++j) acc[i][j] = (f32x4){0.f, 0.f, 0.f, 0.f};

  for (int kt = 0; kt < 1024; kt += 64) {
    #pragma unroll
    for (int c = 0; c < 4; ++c) {
      const int cc = w * 4 + c;
      const int row = cc * 8 + srow;
      gload_lds16(Ag + (size_t)(m0 + row) * 1024 + kt + schunk, As + cc * 512);
      gload_lds16(Bg + (size_t)(n0 + row) * 1024 + kt + schunk, Bs + cc * 512);
    }
    __syncthreads();
    #pragma unroll
    for (int kk = 0; kk < 2; ++kk) {
      const int eo = (kk * 32 + ko) ^ ((qr & 7) << 3);
      bf16x8 afr[4], bfr[4];
      #pragma unroll
      for (int x = 0; x < 4; ++x) {
        afr[x] = *(const bf16x8*)(As + (wm + x * 16 + qr) * 64 + eo);
        bfr[x] = *(const bf16x8*)(Bs + (wn + x * 16 + qr) * 64 + eo);
      }
      #pragma unroll
      for (int mi = 0; mi < 4; ++mi)
        #pragma unroll
        for (int ni = 0; ni < 4; ++ni)
          acc[mi][ni] = __builtin_amdgcn_mfma_f32_16x16x32_bf16(
              afr[mi], bfr[ni], acc[mi][ni], 0, 0, 0);
    }
    __syncthreads();
  }
  #pragma unroll
  for (int ni = 0; ni < 4; ++ni) {
    const int col = n0 + wn + ni * 16 + qr;
    const float bc = bias[col];
    #pragma unroll
    for (int mi = 0; mi < 4; ++mi)
      #pragma unroll
      for (int r = 0; r < 4; ++r) {
        const int row = m0 + wm + mi * 16 + (l >> 4) * 4 + r;
        Cg[(size_t)row * 3072 + col] = (bf16_t)(acc[mi][ni][r] + bc);
      }
  }
}

// ---- Flash attention -------------------------------------------------------
// Block: 256 thr (4 waves), QBLK=128 (wave: 2 q-tiles of 16), KVBLK=64.
// K: 3 LDS buffers via global_load_lds (XOR-swizzled source). V: reg-staged,
// transposed to VT[dv][t] (swizzle S(dv)=(dv&7)<<3 elems) via shfl-paired b32.
__global__ __launch_bounds__(256, 2) void k_attn(const bf16_t* __restrict__ QKV,
                                                 float* __restrict__ out) {
  __shared__ __align__(16) union {
    struct { bf16_t K[3][64 * 128]; bf16_t VT[2][128 * 64]; } st;  // 80 KB
    float Os[4][16 * 132];                                         // 33 KB
  } sm;

  const int tid = threadIdx.x, w = tid >> 6, l = tid & 63;
  const int g = l >> 4, qr = l & 15;
  // XCD-grouped decode: all 16 q-tiles of one (b,h) on one XCD (bid%8 slot).
  const int bid = blockIdx.x;
  const int slot = bid >> 3;
  const int bh = (bid & 7) * 4 + (slot >> 4);
  const int qt = slot & 15;
  const int b = bh >> 3, h = bh & 7;
  const int q0 = qt * 128 + w * 32;

  const bf16_t* Qb = QKV + (size_t)b * 2048 * 3072 + h * 128;
  const bf16_t* Kb = Qb + 1024;
  const bf16_t* Vb = Qb + 2048;

  // Q B-fragments (col q = lane&15, k-feature = g*8+e), held in registers
  bf16x8 aq[2][4];
  #pragma unroll
  for (int mi = 0; mi < 2; ++mi)
    #pragma unroll
    for (int kk = 0; kk < 4; ++kk)
      aq[mi][kk] = *(const bf16x8*)(Qb + (size_t)(q0 + mi * 16 + qr) * 3072 + kk * 32 + g * 8);

  f32x4 o[2][8];
  #pragma unroll
  for (int mi = 0; mi < 2; ++mi)
    #pragma unroll
    for (int d = 0; d < 8; ++d) o[mi][d] = (f32x4){0.f, 0.f, 0.f, 0.f};
  float m0 = -1e30f, m1 = -1e30f, l0 = 0.f, l1 = 0.f;

  // V staging lane constants: lane owns t = w*16 + (l>>2), dv-chunks (l&3)*8 + p*32
  const int vt = w * 16 + (l >> 2);
  const int vc = (l & 3) * 8;
  const int tp2 = (w * 8 + (l >> 3)) * 2;   // t-pair element offset
  const int par = (l >> 2) & 1;

  union U8 { bf16x8 v; u16 u[8]; u32 d[4]; };

  // ---- prologue: stage tile 0 (K -> LDS buf0, V -> regs) ----
  #pragma unroll
  for (int c = 0; c < 4; ++c) {
    const int cc = w * 4 + c;
    const int krow = cc * 4 + g;
    gload_lds16(Kb + (size_t)krow * 3072 + 8 * ((l & 15) ^ (krow & 7)),
                sm.st.K[0] + cc * 512);
  }
  bf16x8 vreg[4], vnext[4];
  #pragma unroll
  for (int p = 0; p < 4; ++p)
    vreg[p] = *(const bf16x8*)(Vb + (size_t)vt * 3072 + vc + p * 32);

  const float sc = 0.08838834764831845f;  // 1/sqrt(128)
  int kc = 0, vbuf = 0;

  for (int it = 0; it < 32; ++it) {
    const int t0 = it * 64;
    // ---- step 1: write VT[vbuf] from vreg (tile it), paired b32 + swizzle ----
    {
      bf16_t* VTw = sm.st.VT[vbuf];
      #pragma unroll
      for (int p = 0; p < 4; ++p) {
        U8 mine, part;
        mine.v = vreg[p];
        #pragma unroll
        for (int q2 = 0; q2 < 4; ++q2) part.d[q2] = __shfl_xor(mine.d[q2], 4);
        #pragma unroll
        for (int jj = 0; jj < 4; ++jj) {
          const int j = par * 4 + jj;
          const int dv = vc + p * 32 + j;
          const u32 val = par ? ((u32)part.u[j] | ((u32)mine.u[j] << 16))
                              : ((u32)mine.u[j] | ((u32)part.u[j] << 16));
          *(u32*)(VTw + dv * 64 + (tp2 ^ (8 * (dv & 7)))) = val;
        }
      }
    }
    // ---- step 2: stage next tile (K -> LDS[kn], V -> vnext regs) ----
    const int kn = (kc == 2) ? 0 : kc + 1;
    if (it < 31) {
      const int tn = t0 + 64;
      #pragma unroll
      for (int c = 0; c < 4; ++c) {
        const int cc = w * 4 + c;
        const int krow = cc * 4 + g;
        gload_lds16(Kb + (size_t)(tn + krow) * 3072 + 8 * ((l & 15) ^ (krow & 7)),
                    sm.st.K[kn] + cc * 512);
      }
      #pragma unroll
      for (int p = 0; p < 4; ++p)
        vnext[p] = *(const bf16x8*)(Vb + (size_t)(tn + vt) * 3072 + vc + p * 32);
    }
    // ---- step 3: counted drain + barrier (keep this iter's 8 loads in flight) ----
    if (it < 31) asm volatile("s_waitcnt vmcnt(8) lgkmcnt(0)" ::: "memory");
    else         asm volatile("s_waitcnt vmcnt(0) lgkmcnt(0)" ::: "memory");
    __builtin_amdgcn_s_barrier();
    __builtin_amdgcn_sched_barrier(0);

    // ---- step 4a: S^T = K Q^T : rows k (ni*16+g*4+r), cols q (lane&15) ----
    const bf16_t* Kc = sm.st.K[kc];
    f32x4 s[2][4];
    #pragma unroll
    for (int mi = 0; mi < 2; ++mi)
      #pragma unroll
      for (int ni = 0; ni < 4; ++ni) s[mi][ni] = (f32x4){0.f, 0.f, 0.f, 0.f};
    __builtin_amdgcn_s_setprio(1);
    #pragma unroll
    for (int kk = 0; kk < 4; ++kk) {
      const int eo = (kk * 32 + g * 8) ^ ((qr & 7) << 3);
      #pragma unroll
      for (int ni = 0; ni < 4; ++ni) {
        const bf16x8 ka = *(const bf16x8*)(Kc + (ni * 16 + qr) * 128 + eo);
        s[0][ni] = __builtin_amdgcn_mfma_f32_16x16x32_bf16(ka, aq[0][kk], s[0][ni], 0, 0, 0);
        s[1][ni] = __builtin_amdgcn_mfma_f32_16x16x32_bf16(ka, aq[1][kk], s[1][ni], 0, 0, 0);
      }
    }
    __builtin_amdgcn_s_setprio(0);

    // ---- step 4b: online softmax, lane-local per q, T13 defer-max ----
    float mx0 = fmaxf(fmaxf(vmax4(s[0][0]), vmax4(s[0][1])),
                      fmaxf(vmax4(s[0][2]), vmax4(s[0][3])));
    float mx1 = fmaxf(fmaxf(vmax4(s[1][0]), vmax4(s[1][1])),
                      fmaxf(vmax4(s[1][2]), vmax4(s[1][3])));
    mx0 = fmaxf(mx0, __shfl_xor(mx0, 16)); mx0 = fmaxf(mx0, __shfl_xor(mx0, 32));
    mx1 = fmaxf(mx1, __shfl_xor(mx1, 16)); mx1 = fmaxf(mx1, __shfl_xor(mx1, 32));
    const float zx0 = mx0 * sc, zx1 = mx1 * sc;
    if (!__all(fmaxf(zx0 - m0, zx1 - m1) <= 8.0f)) {
      const float n0 = fmaxf(m0, zx0), n1 = fmaxf(m1, zx1);
      const float f0 = __expf(m0 - n0), f1 = __expf(m1 - n1);
      l0 *= f0; l1 *= f1; m0 = n0; m1 = n1;
      #pragma unroll
      for (int d = 0; d < 8; ++d) {
        #pragma unroll
        for (int r = 0; r < 4; ++r) { o[0][d][r] *= f0; o[1][d][r] *= f1; }
      }
    }
    s16x4 pf[2][4];
    float ps0 = 0.f, ps1 = 0.f;
    #pragma unroll
    for (int ni = 0; ni < 4; ++ni) {
      bf16x4 t0v, t1v;
      #pragma unroll
      for (int r = 0; r < 4; ++r) {
        const float p0 = __expf(fmaf(s[0][ni][r], sc, -m0));
        const float p1 = __expf(fmaf(s[1][ni][r], sc, -m1));
        ps0 += p0; ps1 += p1;
        t0v[r] = (bf16_t)p0; t1v[r] = (bf16_t)p1;
      }
      pf[0][ni] = __builtin_bit_cast(s16x4, t0v);
      pf[1][ni] = __builtin_bit_cast(s16x4, t1v);
    }
    ps0 += __shfl_xor(ps0, 16); ps0 += __shfl_xor(ps0, 32);
    ps1 += __shfl_xor(ps1, 16); ps1 += __shfl_xor(ps1, 32);
    l0 += ps0; l1 += ps1;

    // ---- step 4c: O^T += V^T P : A = VT[dv=dvt*16+qr][k=ni*16+g*4+e] (b64) ----
    const bf16_t* VTc = sm.st.VT[vbuf];
    #pragma unroll
    for (int ni = 0; ni < 4; ++ni) {
      __builtin_amdgcn_s_setprio(1);
      #pragma unroll
      for (int dvt = 0; dvt < 8; ++dvt) {
        const int dvA = dvt * 16 + qr;
        const s16x4 vf = __builtin_bit_cast(s16x4,
            *(const bf16x4*)(VTc + dvA * 64 + ((ni * 16 + g * 4) ^ (8 * (dvA & 7)))));
        o[0][dvt] = MFMA16(vf, pf[0][ni], o[0][dvt]);
        o[1][dvt] = MFMA16(vf, pf[1][ni], o[1][dvt]);
      }
      __builtin_amdgcn_s_setprio(0);
    }

    // ---- rotate buffers / registers ----
    #pragma unroll
    for (int p = 0; p < 4; ++p) vreg[p] = vnext[p];
    kc = kn; vbuf ^= 1;
  }

  // ---- epilogue: per-wave LDS transpose -> coalesced scrambled write ----
  const float inv0 = 1.0f / l0, inv1 = 1.0f / l1;
  float* Osw = sm.Os[w];
  const size_t obase = ((size_t)b * 2048 + (size_t)h * 256) * 1024;
  #pragma unroll
  for (int mi = 0; mi < 2; ++mi) {
    __syncthreads();  // staging region fully consumed / previous pass done
    const float inv = mi ? inv1 : inv0;
    #pragma unroll
    for (int dvt = 0; dvt < 8; ++dvt)
      #pragma unroll
      for (int r = 0; r < 4; ++r) {
        const float val = (mi ? o[1][dvt][r] : o[0][dvt][r]) * inv;
        Osw[qr * 132 + dvt * 16 + g * 4 + r] = val;
      }
    __syncthreads();
    const int row = l >> 2;            // 0..15 (q within tile)
    const int cb  = (l & 3) * 32;      // 32-float chunk
    const int q = q0 + mi * 16 + row;
    float* dst = out + obase + (size_t)(q >> 3) * 1024 + (q & 7) * 128 + cb;
    #pragma unroll
    for (int e = 0; e < 8; ++e)
      *(float4*)(dst + e * 4) = *(const float4*)(Osw + row * 132 + cb + e * 4);
  }
}

// ---------------------------------------------------------------------------
extern "C" void kernel_launch(void* const* d_in, const int* in_sizes, int n_in,
                              void* d_out, int out_size, void* d_ws, size_t ws_size,
                              hipStream_t stream) {
  const float* x     = (const float*)d_in[0];
  const float* Wq    = (const float*)d_in[1];
  const float* bq    = (const float*)d_in[2];
  const float* Wk    = (const float*)d_in[3];
  const float* bk    = (const float*)d_in[4];
  const float* Wv    = (const float*)d_in[5];
  const float* bv    = (const float*)d_in[6];
  const float* gamma = (const float*)d_in[7];
  const float* beta  = (const float*)d_in[8];
  float* out = (float*)d_out;

  char* ws = (char*)d_ws;
  size_t off = 0;
  bf16_t* WT  = (bf16_t*)(ws + off); off += (size_t)3072 * 1024 * 2;
  float*  bias = (float*)(ws + off); off += (size_t)3072 * 4;
  off = (off + 255) & ~(size_t)255;
  bf16_t* xn  = (bf16_t*)(ws + off); off += (size_t)8192 * 1024 * 2;
  bf16_t* QKV = (bf16_t*)(ws + off); off += (size_t)8192 * 3072 * 2;
  float*  tmp = (float*)(ws + off);  off += (size_t)1024 * 1024 * 4;

  const dim3 tb(32, 8), tg(32, 32);
  k_wvsum<<<1024, 256, 0, stream>>>(Wv, tmp);
  k_transpose<<<tg, tb, 0, stream>>>(Wq, WT);
  k_transpose<<<tg, tb, 0, stream>>>(Wk, WT + (size_t)1024 * 1024);
  k_transpose<<<tg, tb, 0, stream>>>(tmp, WT + (size_t)2048 * 1024);
  k_bias<<<12, 256, 0, stream>>>(bq, bk, bv, bias);
  k_ln<<<8192, 256, 0, stream>>>(x, gamma, beta, xn);
  k_gemm<<<dim3(24, 64), 256, 0, stream>>>(xn, WT, bias, QKV);
  k_attn<<<512, 256, 0, stream>>>(QKV, out);
}